// Round 7
// baseline (288.925 us; speedup 1.0000x reference)
//
#include <hip/hip_runtime.h>
#include <hip/hip_bf16.h>

// Problem constants
#define BATCH 4
#define SEQ   8192
#define DIM   512
#define DD    (DIM*DIM)
#define M_TOT (BATCH*SEQ)   // 32768
#define NCHUNK 512
#define CLEN   16           // SEQ / NCHUNK
#define NSEG   32           // segments per batch-row in pass2 (16 chunks each)

typedef __attribute__((ext_vector_type(4))) int int4v;
typedef __attribute__((ext_vector_type(8))) unsigned short ushort8v;
typedef __attribute__((ext_vector_type(4))) float f4v;

__device__ __forceinline__ float sigmoidf_(float x) {
    return 1.0f / (1.0f + __expf(-x));
}
// g(x) = x>=0 ? x+0.5 : sigmoid(x)
__device__ __forceinline__ float gfun_(float x) {
    return (x >= 0.0f) ? (x + 0.5f) : sigmoidf_(x);
}

__device__ __forceinline__ void stage16(const void* g, void* lds) {
    __builtin_amdgcn_global_load_lds((const __attribute__((address_space(1))) void*)g,
                                     (__attribute__((address_space(3))) void*)lds,
                                     16, 0, 0);
}

// ---------------- quantization kernels ----------------
// x scale 2048 -> 16-bit, split into signed hi/lo i8 digits
__global__ __launch_bounds__(256) void quant_x(const float* __restrict__ x,
                                               char* __restrict__ xh, char* __restrict__ xl)
{
    const int t = blockIdx.x * 256 + threadIdx.x;        // one float4 per thread
    float4 v = ((const float4*)x)[t];
    float vals[4] = {v.x, v.y, v.z, v.w};
    char hs[4], ls[4];
    #pragma unroll
    for (int e = 0; e < 4; ++e) {
        float c = fminf(fmaxf(vals[e], -15.8f), 15.8f);
        int q = (int)rintf(c * 2048.0f);
        int hi = (q + 128) >> 8;
        int lo = q - (hi << 8);
        hs[e] = (char)hi; ls[e] = (char)lo;
    }
    char4 hv = {hs[0], hs[1], hs[2], hs[3]};
    char4 lv = {ls[0], ls[1], ls[2], ls[3]};
    *(char4*)&xh[(size_t)t * 4] = hv;
    *(char4*)&xl[(size_t)t * 4] = lv;
}

// W: read [k][n], write transposed [n][k], scale 65536, split hi/lo i8.
__global__ __launch_bounds__(256) void quant_wT(
    const float* __restrict__ Wf, const float* __restrict__ Wi, const float* __restrict__ Wh,
    char* __restrict__ wth, char* __restrict__ wtl)
{
    __shared__ float tile[64][65];
    const int g = blockIdx.z;
    const float* W = (g == 0) ? Wf : (g == 1) ? Wi : Wh;
    const int k0 = blockIdx.x * 64, n0 = blockIdx.y * 64;
    const int c = threadIdx.x & 63, r4 = threadIdx.x >> 6;
    #pragma unroll
    for (int p = 0; p < 16; ++p) {
        int r = p * 4 + r4;
        tile[r][c] = W[(size_t)(k0 + r) * DIM + n0 + c];
    }
    __syncthreads();
    const size_t gbase = (size_t)g * DD;
    #pragma unroll
    for (int p = 0; p < 16; ++p) {
        int nr = p * 4 + r4;                 // local n
        float w = tile[c][nr];               // (k = k0+c, n = n0+nr)
        float cl = fminf(fmaxf(w, -0.49f), 0.49f);
        int q = (int)rintf(cl * 65536.0f);
        int hi = (q + 128) >> 8;
        int lo = q - (hi << 8);
        size_t o = gbase + (size_t)(n0 + nr) * DIM + k0 + c;
        wth[o] = (char)hi;
        wtl[o] = (char)lo;
    }
}

// ---------------- f-gate GEMM (r5-proven): 1024 blocks, 64KB LDS, fp32 stores ----
__global__ __launch_bounds__(512, 4) void gemm_f(
    const char* __restrict__ xh, const char* __restrict__ xl,
    const char* __restrict__ wth, const char* __restrict__ wtl,
    const float* __restrict__ bfv, float* __restrict__ fb)
{
    __shared__ char smem[65536];
    char (*sA)[2][128][64] = (char (*)[2][128][64])smem;            // [buf][dig][m][k]
    char (*sB)[2][128][64] = (char (*)[2][128][64])(smem + 32768);  // [buf][dig][n][k]

    const int bid = blockIdx.x;          // 1024 = 8 xcd * 128
    const int xr  = bid & 7;
    const int t   = bid >> 3;            // 0..127
    const int mmt = t >> 2;              // 0..31
    const int n0  = (t & 3) * 128;
    const int m0  = (xr + (mmt << 3)) * 128;

    const int tid  = threadIdx.x;
    const int wave = tid >> 6;
    const int lane = tid & 63;
    const int wi = wave >> 2, wj = wave & 3;   // 2x4 waves of 64m x 32n

    const int smm  = tid >> 2;                       // row 0..127
    const int skb  = (tid & 3) * 16;
    const int sksw = skb ^ (((smm >> 1) & 3) << 4);
    const int swrow = (tid >> 6) * 16;               // wave-uniform LDS base row
    const char* gx_h = xh  + (size_t)(m0 + smm) * DIM + sksw;
    const char* gx_l = xl  + (size_t)(m0 + smm) * DIM + sksw;
    const char* gw_h = wth + (size_t)(n0 + smm) * DIM + sksw;    // g=0 plane
    const char* gw_l = wtl + (size_t)(n0 + smm) * DIM + sksw;

    int4v P2[4][2], P1[4][2];
    const int4v zero = {0, 0, 0, 0};
    #pragma unroll
    for (int i = 0; i < 4; ++i)
        #pragma unroll
        for (int j = 0; j < 2; ++j) { P2[i][j] = zero; P1[i][j] = zero; }

    stage16(gx_h, &sA[0][0][swrow][0]);
    stage16(gx_l, &sA[0][1][swrow][0]);
    stage16(gw_h, &sB[0][0][swrow][0]);
    stage16(gw_l, &sB[0][1][swrow][0]);

    #pragma unroll
    for (int kt = 0; kt < 8; ++kt) {
        const int cur = kt & 1;
        if (kt < 7) {
            const int nb = cur ^ 1;
            const int ko = (kt + 1) * 64;
            stage16(gx_h + ko, &sA[nb][0][swrow][0]);
            stage16(gx_l + ko, &sA[nb][1][swrow][0]);
            stage16(gw_h + ko, &sB[nb][0][swrow][0]);
            stage16(gw_l + ko, &sB[nb][1][swrow][0]);
            asm volatile("s_waitcnt vmcnt(4)" ::: "memory");
        } else {
            asm volatile("s_waitcnt vmcnt(0)" ::: "memory");
        }
        asm volatile("s_barrier" ::: "memory");

        const int kseg = (lane >> 4) * 16;
        int4v bhf[2], blf[2];
        #pragma unroll
        for (int j = 0; j < 2; ++j) {
            const int col = wj * 32 + j * 16 + (lane & 15);
            const int ks  = kseg ^ (((col >> 1) & 3) << 4);
            bhf[j] = *(const int4v*)&sB[cur][0][col][ks];
            blf[j] = *(const int4v*)&sB[cur][1][col][ks];
        }
        __builtin_amdgcn_s_setprio(1);
        #pragma unroll
        for (int i = 0; i < 4; ++i) {
            const int row = wi * 64 + i * 16 + (lane & 15);
            const int ks  = kseg ^ (((row >> 1) & 3) << 4);
            int4v ahf = *(const int4v*)&sA[cur][0][row][ks];
            int4v alf = *(const int4v*)&sA[cur][1][row][ks];
            #pragma unroll
            for (int j = 0; j < 2; ++j) {
                P2[i][j] = __builtin_amdgcn_mfma_i32_16x16x64_i8(ahf, bhf[j], P2[i][j], 0, 0, 0);
                P1[i][j] = __builtin_amdgcn_mfma_i32_16x16x64_i8(ahf, blf[j], P1[i][j], 0, 0, 0);
                P1[i][j] = __builtin_amdgcn_mfma_i32_16x16x64_i8(alf, bhf[j], P1[i][j], 0, 0, 0);
            }
        }
        __builtin_amdgcn_s_setprio(0);
        asm volatile("s_barrier" ::: "memory");
    }

    // epilogue: f = sigmoid(k), fp32 direct stores (r1-proven)
    const float c2 = 1.0f / 2048.0f;
    const float c1 = 1.0f / 524288.0f;
    #pragma unroll
    for (int j = 0; j < 2; ++j) {
        const int col = n0 + wj * 32 + j * 16 + (lane & 15);
        const float bv = bfv[col];
        #pragma unroll
        for (int i = 0; i < 4; ++i) {
            #pragma unroll
            for (int r = 0; r < 4; ++r) {
                const float kv = (float)P2[i][j][r] * c2 + (float)P1[i][j][r] * c1 + bv;
                const int row = m0 + wi * 64 + i * 16 + (lane >> 4) * 4 + r;
                fb[(size_t)row * DIM + col] = sigmoidf_(kv);
            }
        }
    }
}

// ---------------- fused i+h GEMM: 64m x 128n tiles, 2048 blocks, 80KB LDS ----
// 2 blocks/CU (80KB of 160KB; acc 64 VGPR). Per-wave 32m x 32n.
// Staging: 5 DMAs/thread/ktile (4 B + 1 A) -> counted vmcnt(5).
__global__ __launch_bounds__(512, 4) void gemm_ih(
    const char* __restrict__ xh, const char* __restrict__ xl,
    const char* __restrict__ wth, const char* __restrict__ wtl,
    const float* __restrict__ biv, const float* __restrict__ bhv,
    unsigned short* __restrict__ vb)
{
    extern __shared__ char smem[];
    char (*sA)[2][64][64]     = (char (*)[2][64][64])smem;               // [buf][dig][m][k] 16KB
    char (*sB)[2][2][128][64] = (char (*)[2][2][128][64])(smem + 16384); // [buf][gate][dig][n][k] 64KB
    unsigned short (*lds16)[136] = (unsigned short (*)[136])smem;        // epilogue transpose

    const int bid = blockIdx.x;          // 2048 = 8 xcd * 256
    const int xr  = bid & 7;
    const int t   = bid >> 3;            // 0..255
    const int mmt = t >> 2;              // 0..63
    const int n0  = (t & 3) * 128;
    const int m0  = (xr + (mmt << 3)) * 64;

    const int tid  = threadIdx.x;
    const int wave = tid >> 6;
    const int lane = tid & 63;
    const int wi = wave >> 2, wj = wave & 3;   // 2x4 waves of 32m x 32n

    // B staging geometry (r5-proven): each thread stages 4x 16B (2 gates x 2 digits)
    const int smm  = tid >> 2;                       // row 0..127
    const int skb  = (tid & 3) * 16;
    const int sksw = skb ^ (((smm >> 1) & 3) << 4);
    const int swrow = wave * 16;                     // wave-uniform LDS base row
    const char* gwi_h = wth + (size_t)1 * DD + (size_t)(n0 + smm) * DIM + sksw;
    const char* gwi_l = wtl + (size_t)1 * DD + (size_t)(n0 + smm) * DIM + sksw;
    const char* gwh_h = wth + (size_t)2 * DD + (size_t)(n0 + smm) * DIM + sksw;
    const char* gwh_l = wtl + (size_t)2 * DD + (size_t)(n0 + smm) * DIM + sksw;

    // A staging geometry: one 16B DMA per thread. Waves 0-3 -> digit 0, 4-7 -> digit 1.
    const int adig  = tid >> 8;                      // wave-uniform (0 or 1)
    const int arow  = (tid & 255) >> 2;              // 0..63
    const int abyte = (tid & 3) * 16;
    const int asw   = abyte ^ (((arow >> 1) & 3) << 4);
    const int awrow = (wave & 3) * 16;               // wave-uniform LDS base row
    const char* ga = (adig ? xl : xh) + (size_t)(m0 + arow) * DIM + asw;

    int4v Pi2[2][2], Pi1[2][2], Ph2[2][2], Ph1[2][2];
    const int4v zero = {0, 0, 0, 0};
    #pragma unroll
    for (int i = 0; i < 2; ++i)
        #pragma unroll
        for (int j = 0; j < 2; ++j) {
            Pi2[i][j] = zero; Pi1[i][j] = zero;
            Ph2[i][j] = zero; Ph1[i][j] = zero;
        }

    // stage k-tile 0 into buf 0: B(4) + A(1)
    stage16(gwi_h, &sB[0][0][0][swrow][0]);
    stage16(gwi_l, &sB[0][0][1][swrow][0]);
    stage16(gwh_h, &sB[0][1][0][swrow][0]);
    stage16(gwh_l, &sB[0][1][1][swrow][0]);
    stage16(ga,    &sA[0][adig][awrow][0]);

    #pragma unroll
    for (int kt = 0; kt < 8; ++kt) {
        const int cur = kt & 1;
        if (kt < 7) {
            const int nb = cur ^ 1;
            const int ko = (kt + 1) * 64;
            stage16(gwi_h + ko, &sB[nb][0][0][swrow][0]);
            stage16(gwi_l + ko, &sB[nb][0][1][swrow][0]);
            stage16(gwh_h + ko, &sB[nb][1][0][swrow][0]);
            stage16(gwh_l + ko, &sB[nb][1][1][swrow][0]);
            stage16(ga + ko,    &sA[nb][adig][awrow][0]);
            // wait for CURRENT tile's 5 DMAs; the 5 just-issued stay in flight
            asm volatile("s_waitcnt vmcnt(5)" ::: "memory");
        } else {
            asm volatile("s_waitcnt vmcnt(0)" ::: "memory");
        }
        asm volatile("s_barrier" ::: "memory");

        const int kseg = (lane >> 4) * 16;
        int4v bih[2], bil[2], bhh[2], bhl[2];
        #pragma unroll
        for (int j = 0; j < 2; ++j) {
            const int col = wj * 32 + j * 16 + (lane & 15);
            const int ks  = kseg ^ (((col >> 1) & 3) << 4);
            bih[j] = *(const int4v*)&sB[cur][0][0][col][ks];
            bil[j] = *(const int4v*)&sB[cur][0][1][col][ks];
            bhh[j] = *(const int4v*)&sB[cur][1][0][col][ks];
            bhl[j] = *(const int4v*)&sB[cur][1][1][col][ks];
        }
        __builtin_amdgcn_s_setprio(1);
        #pragma unroll
        for (int i = 0; i < 2; ++i) {
            const int row = wi * 32 + i * 16 + (lane & 15);
            const int ks  = kseg ^ (((row >> 1) & 3) << 4);
            int4v ahf = *(const int4v*)&sA[cur][0][row][ks];
            int4v alf = *(const int4v*)&sA[cur][1][row][ks];
            #pragma unroll
            for (int j = 0; j < 2; ++j) {
                Pi2[i][j] = __builtin_amdgcn_mfma_i32_16x16x64_i8(ahf, bih[j], Pi2[i][j], 0, 0, 0);
                Pi1[i][j] = __builtin_amdgcn_mfma_i32_16x16x64_i8(ahf, bil[j], Pi1[i][j], 0, 0, 0);
                Pi1[i][j] = __builtin_amdgcn_mfma_i32_16x16x64_i8(alf, bih[j], Pi1[i][j], 0, 0, 0);
                Ph2[i][j] = __builtin_amdgcn_mfma_i32_16x16x64_i8(ahf, bhh[j], Ph2[i][j], 0, 0, 0);
                Ph1[i][j] = __builtin_amdgcn_mfma_i32_16x16x64_i8(ahf, bhl[j], Ph1[i][j], 0, 0, 0);
                Ph1[i][j] = __builtin_amdgcn_mfma_i32_16x16x64_i8(alf, bhh[j], Ph1[i][j], 0, 0, 0);
            }
        }
        __builtin_amdgcn_s_setprio(0);
        asm volatile("s_barrier" ::: "memory");
    }

    // ---- epilogue: v = sigmoid(ki) * g(kh) -> u16 (scale 8192), LDS transpose ----
    const float c2 = 1.0f / 2048.0f;
    const float c1 = 1.0f / 524288.0f;
    #pragma unroll
    for (int j = 0; j < 2; ++j) {
        const int lc = wj * 32 + j * 16 + (lane & 15);
        const float bvi = biv[n0 + lc];
        const float bvh = bhv[n0 + lc];
        #pragma unroll
        for (int i = 0; i < 2; ++i) {
            #pragma unroll
            for (int r = 0; r < 4; ++r) {
                const float ki = (float)Pi2[i][j][r] * c2 + (float)Pi1[i][j][r] * c1 + bvi;
                const float kh = (float)Ph2[i][j][r] * c2 + (float)Ph1[i][j][r] * c1 + bvh;
                const float v  = sigmoidf_(ki) * gfun_(kh);
                const int lr = wi * 32 + i * 16 + (lane >> 4) * 4 + r;
                lds16[lr][lc] = (unsigned short)fminf(rintf(v * 8192.0f), 65535.0f);
            }
        }
    }
    __syncthreads();
    const int r  = tid >> 3;        // row 0..63
    const int cq = tid & 7;         // base chunk
    #pragma unroll
    for (int it = 0; it < 2; ++it) {
        const int ci = cq + it * 8;                 // 16B chunk 0..15
        ushort8v vv = *(const ushort8v*)&lds16[r][ci * 8];
        *(ushort8v*)&vb[(size_t)(m0 + r) * DIM + n0 + ci * 8] = vv;
    }
}

// v stored at scale 8192
#define VSCALE (1.0f / 8192.0f)

// ---------------- scan kernels (r5-proven, occupancy-rebuilt) ----------------
__global__ __launch_bounds__(256) void scan_pass1(
    const float* __restrict__ fb, const unsigned short* __restrict__ vb,
    float* __restrict__ Ach, float* __restrict__ Bch)
{
    const int dq  = threadIdx.x & 127;            // d/4
    const int sub = threadIdx.x >> 7;
    const int c = blockIdx.x * 2 + sub;
    const int b = blockIdx.y;
    const int d = dq * 4;
    float A[4] = {1.f, 1.f, 1.f, 1.f};
    float B[4] = {0.f, 0.f, 0.f, 0.f};
    size_t base = ((size_t)(b * SEQ + c * CLEN)) * DIM + d;
    #pragma unroll 4
    for (int t = 0; t < CLEN; ++t) {
        float4  f4 = *(const float4*)&fb[base + (size_t)t * DIM];
        ushort4 v4 = *(const ushort4*)&vb[base + (size_t)t * DIM];
        float f[4] = {f4.x, f4.y, f4.z, f4.w};
        float v[4] = {(float)v4.x * VSCALE, (float)v4.y * VSCALE,
                      (float)v4.z * VSCALE, (float)v4.w * VSCALE};
        #pragma unroll
        for (int e = 0; e < 4; ++e) { B[e] = fmaf(f[e], B[e], v[e]); A[e] *= f[e]; }
    }
    const size_t idx = (size_t)(b * NCHUNK + c) * DIM + d;
    *(float4*)&Ach[idx] = *(float4*)A;
    *(float4*)&Bch[idx] = *(float4*)B;
}

// pass2: hierarchical chunk-carry in one kernel (see r5 notes).
__global__ __launch_bounds__(1024) void scan_pass2(
    const float* __restrict__ pre_h,
    const float* __restrict__ Ach, const float* __restrict__ Bch,
    float* __restrict__ carry)
{
    __shared__ float As[NSEG][33], Bs[NSEG][33];
    const int b    = blockIdx.y;
    const int dgrp = blockIdx.x;
    const int seg  = threadIdx.x >> 5;
    const int dl   = threadIdx.x & 31;
    const int d    = dgrp * 32 + dl;
    const int c0   = seg * 16;

    float A = 1.0f, Bv = 0.0f;
    #pragma unroll 4
    for (int cc = 0; cc < 16; ++cc) {
        const size_t ix = (size_t)(b * NCHUNK + c0 + cc) * DIM + d;
        const float a  = Ach[ix];
        const float bb = Bch[ix];
        Bv = fmaf(a, Bv, bb);
        A *= a;
    }
    As[seg][dl] = A;
    Bs[seg][dl] = Bv;
    __syncthreads();

    float Ai = A, Bi = Bv;
    #pragma unroll
    for (int s = 1; s < NSEG; s <<= 1) {
        float Al = 1.0f, Bl = 0.0f;
        const bool act = (seg >= s);
        if (act) { Al = As[seg - s][dl]; Bl = Bs[seg - s][dl]; }
        __syncthreads();
        if (act) {
            Bi = fmaf(Ai, Bl, Bi);
            Ai = Ai * Al;
            As[seg][dl] = Ai;
            Bs[seg][dl] = Bi;
        }
        __syncthreads();
    }

    const float h0 = gfun_(pre_h[b * DIM + d]);
    float h;
    if (seg == 0) h = h0;
    else          h = fmaf(As[seg - 1][dl], h0, Bs[seg - 1][dl]);

    #pragma unroll 4
    for (int cc = 0; cc < 16; ++cc) {
        const size_t ix = (size_t)(b * NCHUNK + c0 + cc) * DIM + d;
        carry[ix] = h;
        h = fmaf(Ach[ix], h, Bch[ix]);
    }
}

__global__ __launch_bounds__(256) void scan_pass3(
    const float* __restrict__ fb, const unsigned short* __restrict__ vb,
    const float* __restrict__ carry, float* __restrict__ out)
{
    const int dq  = threadIdx.x & 127;
    const int sub = threadIdx.x >> 7;
    const int c = blockIdx.x * 2 + sub;
    const int b = blockIdx.y;
    const int d = dq * 4;
    float4 h4 = *(const float4*)&carry[(size_t)(b * NCHUNK + c) * DIM + d];
    float h[4] = {h4.x, h4.y, h4.z, h4.w};
    size_t base = ((size_t)(b * SEQ + c * CLEN)) * DIM + d;
    #pragma unroll 4
    for (int t = 0; t < CLEN; ++t) {
        float4  f4 = *(const float4*)&fb[base + (size_t)t * DIM];
        ushort4 v4 = *(const ushort4*)&vb[base + (size_t)t * DIM];
        float f[4] = {f4.x, f4.y, f4.z, f4.w};
        float v[4] = {(float)v4.x * VSCALE, (float)v4.y * VSCALE,
                      (float)v4.z * VSCALE, (float)v4.w * VSCALE};
        f4v o;
        #pragma unroll
        for (int e = 0; e < 4; ++e) { h[e] = fmaf(f[e], h[e], v[e]); o[e] = h[e]; }
        __builtin_nontemporal_store(o, (f4v*)&out[base + (size_t)t * DIM]);
    }
}

extern "C" void kernel_launch(void* const* d_in, const int* in_sizes, int n_in,
                              void* d_out, int out_size, void* d_ws, size_t ws_size,
                              hipStream_t stream) {
    const float* x     = (const float*)d_in[0];
    const float* pre_h = (const float*)d_in[1];
    const float* Wf    = (const float*)d_in[2];
    const float* bf    = (const float*)d_in[3];
    const float* Wi    = (const float*)d_in[4];
    const float* bi    = (const float*)d_in[5];
    const float* Wh    = (const float*)d_in[6];
    const float* bh    = (const float*)d_in[7];
    float* out = (float*)d_out;

    char* ws = (char*)d_ws;
    const size_t XQ = (size_t)M_TOT * DIM;                  // 16 MB per i8 plane
    const size_t WQ = (size_t)3 * DD;                       // 768 KB per digit
    const size_t FB = (size_t)M_TOT * DIM * sizeof(float);  // 64 MB fp32 f plane
    const size_t VB = (size_t)M_TOT * DIM * 2;              // 32 MB u16 v plane
    const size_t CH = (size_t)BATCH * NCHUNK * DIM * sizeof(float);  // 4 MB

    char*  xh  = ws;
    char*  xl  = ws + XQ;
    char*  wth = ws + 2 * XQ;
    char*  wtl = ws + 2 * XQ + WQ;
    float* fbuf = (float*)(ws + 2 * XQ + 2 * WQ);
    unsigned short* vbuf = (unsigned short*)((char*)fbuf + FB);
    float* Ach   = (float*)((char*)vbuf + VB);
    float* Bch   = (float*)((char*)Ach + CH);
    float* carry = (float*)((char*)Bch + CH);

    static bool attr_set = false;
    if (!attr_set) {
        hipFuncSetAttribute((const void*)gemm_ih,
                            hipFuncAttributeMaxDynamicSharedMemorySize, 81920);
        attr_set = true;
    }

    quant_x<<<(M_TOT * DIM / 4) / 256, 256, 0, stream>>>(x, xh, xl);
    quant_wT<<<dim3(8, 8, 3), 256, 0, stream>>>(Wf, Wi, Wh, wth, wtl);
    gemm_f<<<1024, 512, 0, stream>>>(xh, xl, wth, wtl, bf, fbuf);
    gemm_ih<<<2048, 512, 81920, stream>>>(xh, xl, wth, wtl, bi, bh, vbuf);
    scan_pass1<<<dim3(NCHUNK / 2, BATCH), 256, 0, stream>>>(fbuf, vbuf, Ach, Bch);
    scan_pass2<<<dim3(DIM / 32, BATCH), 1024, 0, stream>>>(pre_h, Ach, Bch, carry);
    scan_pass3<<<dim3(NCHUNK / 2, BATCH), 256, 0, stream>>>(fbuf, vbuf, carry, out);
}

// Round 8
// 272.888 us; speedup vs baseline: 1.0588x; 1.0588x over previous
//
#include <hip/hip_runtime.h>
#include <hip/hip_bf16.h>

// Problem constants
#define BATCH 4
#define SEQ   8192
#define DIM   512
#define DD    (DIM*DIM)
#define M_TOT (BATCH*SEQ)   // 32768
#define NCHUNK 512
#define CLEN   16           // SEQ / NCHUNK
#define NSEG   32           // segments per batch-row in pass2 (16 chunks each)

typedef __attribute__((ext_vector_type(4))) int int4v;
typedef __attribute__((ext_vector_type(8))) unsigned short ushort8v;
typedef __attribute__((ext_vector_type(4))) float f4v;

__device__ __forceinline__ float sigmoidf_(float x) {
    return 1.0f / (1.0f + __expf(-x));
}
// g(x) = x>=0 ? x+0.5 : sigmoid(x)
__device__ __forceinline__ float gfun_(float x) {
    return (x >= 0.0f) ? (x + 0.5f) : sigmoidf_(x);
}

__device__ __forceinline__ void stage16(const void* g, void* lds) {
    __builtin_amdgcn_global_load_lds((const __attribute__((address_space(1))) void*)g,
                                     (__attribute__((address_space(3))) void*)lds,
                                     16, 0, 0);
}

// ---------------- merged quantization: x blocks [0,16384), W blocks [16384,16576) ----
__global__ __launch_bounds__(256) void quant_all(
    const float* __restrict__ x, char* __restrict__ xh, char* __restrict__ xl,
    const float* __restrict__ Wf, const float* __restrict__ Wi, const float* __restrict__ Wh,
    char* __restrict__ wth, char* __restrict__ wtl)
{
    __shared__ float tile[64][65];
    if (blockIdx.x < 16384) {
        // x scale 2048 -> 16-bit, split into signed hi/lo i8 digits
        const int t = blockIdx.x * 256 + threadIdx.x;        // one float4 per thread
        float4 v = ((const float4*)x)[t];
        float vals[4] = {v.x, v.y, v.z, v.w};
        char hs[4], ls[4];
        #pragma unroll
        for (int e = 0; e < 4; ++e) {
            float c = fminf(fmaxf(vals[e], -15.8f), 15.8f);
            int q = (int)rintf(c * 2048.0f);
            int hi = (q + 128) >> 8;
            int lo = q - (hi << 8);
            hs[e] = (char)hi; ls[e] = (char)lo;
        }
        char4 hv = {hs[0], hs[1], hs[2], hs[3]};
        char4 lv = {ls[0], ls[1], ls[2], ls[3]};
        *(char4*)&xh[(size_t)t * 4] = hv;
        *(char4*)&xl[(size_t)t * 4] = lv;
    } else {
        // W: read [k][n], write transposed [n][k], scale 65536, split hi/lo i8.
        const int idx = blockIdx.x - 16384;      // 0..191
        const int g   = idx >> 6;
        const int rr  = idx & 63;
        const int k0  = (rr & 7) * 64, n0 = (rr >> 3) * 64;
        const float* W = (g == 0) ? Wf : (g == 1) ? Wi : Wh;
        const int c = threadIdx.x & 63, r4 = threadIdx.x >> 6;
        #pragma unroll
        for (int p = 0; p < 16; ++p) {
            int r = p * 4 + r4;
            tile[r][c] = W[(size_t)(k0 + r) * DIM + n0 + c];
        }
        __syncthreads();
        const size_t gbase = (size_t)g * DD;
        #pragma unroll
        for (int p = 0; p < 16; ++p) {
            int nr = p * 4 + r4;                 // local n
            float w = tile[c][nr];               // (k = k0+c, n = n0+nr)
            float cl = fminf(fmaxf(w, -0.49f), 0.49f);
            int q = (int)rintf(cl * 65536.0f);
            int hi = (q + 128) >> 8;
            int lo = q - (hi << 8);
            size_t o = gbase + (size_t)(n0 + nr) * DIM + k0 + c;
            wth[o] = (char)hi;
            wtl[o] = (char)lo;
        }
    }
}

// ---------------- merged GEMM: ih tiles (2048) + f tiles (1024) in one launch ----
// Block group of 12 = 8 ih + 4 f (co-resident mixing; both paths 2 blocks/CU at
// 80KB dynamic LDS, 512 thr). Each path's internal math is the proven r5/r7 code.
__global__ __launch_bounds__(512, 4) void gemm_fih(
    const char* __restrict__ xh, const char* __restrict__ xl,
    const char* __restrict__ wth, const char* __restrict__ wtl,
    const float* __restrict__ bfv, const float* __restrict__ biv, const float* __restrict__ bhv,
    float* __restrict__ fb, unsigned short* __restrict__ vb)
{
    extern __shared__ char smem[];
    const int gid = blockIdx.x;          // 0..3071
    const int grp = gid / 12;            // 0..255
    const int rr  = gid - grp * 12;      // 0..11

    const int tid  = threadIdx.x;
    const int wave = tid >> 6;
    const int lane = tid & 63;
    const int wi = wave >> 2, wj = wave & 3;
    const int4v zero = {0, 0, 0, 0};
    const float c2 = 1.0f / 2048.0f;
    const float c1 = 1.0f / 524288.0f;

    if (rr >= 8) {
        // ================= f path (r5-proven): 128m x 128n, 64KB LDS =================
        char (*sA)[2][128][64] = (char (*)[2][128][64])smem;            // [buf][dig][m][k]
        char (*sB)[2][128][64] = (char (*)[2][128][64])(smem + 32768);  // [buf][dig][n][k]

        const int bid = grp * 4 + (rr - 8);  // 0..1023
        const int xr  = bid & 7;
        const int t   = bid >> 3;
        const int mmt = t >> 2;
        const int n0  = (t & 3) * 128;
        const int m0  = (xr + (mmt << 3)) * 128;

        const int smm  = tid >> 2;
        const int skb  = (tid & 3) * 16;
        const int sksw = skb ^ (((smm >> 1) & 3) << 4);
        const int swrow = (tid >> 6) * 16;
        const char* gx_h = xh  + (size_t)(m0 + smm) * DIM + sksw;
        const char* gx_l = xl  + (size_t)(m0 + smm) * DIM + sksw;
        const char* gw_h = wth + (size_t)(n0 + smm) * DIM + sksw;
        const char* gw_l = wtl + (size_t)(n0 + smm) * DIM + sksw;

        int4v P2[4][2], P1[4][2];
        #pragma unroll
        for (int i = 0; i < 4; ++i)
            #pragma unroll
            for (int j = 0; j < 2; ++j) { P2[i][j] = zero; P1[i][j] = zero; }

        stage16(gx_h, &sA[0][0][swrow][0]);
        stage16(gx_l, &sA[0][1][swrow][0]);
        stage16(gw_h, &sB[0][0][swrow][0]);
        stage16(gw_l, &sB[0][1][swrow][0]);

        #pragma unroll
        for (int kt = 0; kt < 8; ++kt) {
            const int cur = kt & 1;
            if (kt < 7) {
                const int nb = cur ^ 1;
                const int ko = (kt + 1) * 64;
                stage16(gx_h + ko, &sA[nb][0][swrow][0]);
                stage16(gx_l + ko, &sA[nb][1][swrow][0]);
                stage16(gw_h + ko, &sB[nb][0][swrow][0]);
                stage16(gw_l + ko, &sB[nb][1][swrow][0]);
                asm volatile("s_waitcnt vmcnt(4)" ::: "memory");
            } else {
                asm volatile("s_waitcnt vmcnt(0)" ::: "memory");
            }
            asm volatile("s_barrier" ::: "memory");

            const int kseg = (lane >> 4) * 16;
            int4v bhf[2], blf[2];
            #pragma unroll
            for (int j = 0; j < 2; ++j) {
                const int col = wj * 32 + j * 16 + (lane & 15);
                const int ks  = kseg ^ (((col >> 1) & 3) << 4);
                bhf[j] = *(const int4v*)&sB[cur][0][col][ks];
                blf[j] = *(const int4v*)&sB[cur][1][col][ks];
            }
            __builtin_amdgcn_s_setprio(1);
            #pragma unroll
            for (int i = 0; i < 4; ++i) {
                const int row = wi * 64 + i * 16 + (lane & 15);
                const int ks  = kseg ^ (((row >> 1) & 3) << 4);
                int4v ahf = *(const int4v*)&sA[cur][0][row][ks];
                int4v alf = *(const int4v*)&sA[cur][1][row][ks];
                #pragma unroll
                for (int j = 0; j < 2; ++j) {
                    P2[i][j] = __builtin_amdgcn_mfma_i32_16x16x64_i8(ahf, bhf[j], P2[i][j], 0, 0, 0);
                    P1[i][j] = __builtin_amdgcn_mfma_i32_16x16x64_i8(ahf, blf[j], P1[i][j], 0, 0, 0);
                    P1[i][j] = __builtin_amdgcn_mfma_i32_16x16x64_i8(alf, bhf[j], P1[i][j], 0, 0, 0);
                }
            }
            __builtin_amdgcn_s_setprio(0);
            asm volatile("s_barrier" ::: "memory");
        }

        // epilogue: f = sigmoid(k), fp32 direct stores
        #pragma unroll
        for (int j = 0; j < 2; ++j) {
            const int col = n0 + wj * 32 + j * 16 + (lane & 15);
            const float bv = bfv[col];
            #pragma unroll
            for (int i = 0; i < 4; ++i) {
                #pragma unroll
                for (int r = 0; r < 4; ++r) {
                    const float kv = (float)P2[i][j][r] * c2 + (float)P1[i][j][r] * c1 + bv;
                    const int row = m0 + wi * 64 + i * 16 + (lane >> 4) * 4 + r;
                    fb[(size_t)row * DIM + col] = sigmoidf_(kv);
                }
            }
        }
    } else {
        // ================= ih path (r7-proven): 64m x 128n, 80KB LDS =================
        char (*sA)[2][64][64]     = (char (*)[2][64][64])smem;               // [buf][dig][m][k]
        char (*sB)[2][2][128][64] = (char (*)[2][2][128][64])(smem + 16384); // [buf][gate][dig][n][k]
        unsigned short (*lds16)[136] = (unsigned short (*)[136])smem;        // epilogue transpose

        const int bid = grp * 8 + rr;        // 0..2047
        const int xr  = bid & 7;
        const int t   = bid >> 3;
        const int mmt = t >> 2;
        const int n0  = (t & 3) * 128;
        const int m0  = (xr + (mmt << 3)) * 64;

        const int smm  = tid >> 2;
        const int skb  = (tid & 3) * 16;
        const int sksw = skb ^ (((smm >> 1) & 3) << 4);
        const int swrow = wave * 16;
        const char* gwi_h = wth + (size_t)1 * DD + (size_t)(n0 + smm) * DIM + sksw;
        const char* gwi_l = wtl + (size_t)1 * DD + (size_t)(n0 + smm) * DIM + sksw;
        const char* gwh_h = wth + (size_t)2 * DD + (size_t)(n0 + smm) * DIM + sksw;
        const char* gwh_l = wtl + (size_t)2 * DD + (size_t)(n0 + smm) * DIM + sksw;

        const int adig  = tid >> 8;
        const int arow  = (tid & 255) >> 2;
        const int abyte = (tid & 3) * 16;
        const int asw   = abyte ^ (((arow >> 1) & 3) << 4);
        const int awrow = (wave & 3) * 16;
        const char* ga = (adig ? xl : xh) + (size_t)(m0 + arow) * DIM + asw;

        int4v Pi2[2][2], Pi1[2][2], Ph2[2][2], Ph1[2][2];
        #pragma unroll
        for (int i = 0; i < 2; ++i)
            #pragma unroll
            for (int j = 0; j < 2; ++j) {
                Pi2[i][j] = zero; Pi1[i][j] = zero;
                Ph2[i][j] = zero; Ph1[i][j] = zero;
            }

        stage16(gwi_h, &sB[0][0][0][swrow][0]);
        stage16(gwi_l, &sB[0][0][1][swrow][0]);
        stage16(gwh_h, &sB[0][1][0][swrow][0]);
        stage16(gwh_l, &sB[0][1][1][swrow][0]);
        stage16(ga,    &sA[0][adig][awrow][0]);

        #pragma unroll
        for (int kt = 0; kt < 8; ++kt) {
            const int cur = kt & 1;
            if (kt < 7) {
                const int nb = cur ^ 1;
                const int ko = (kt + 1) * 64;
                stage16(gwi_h + ko, &sB[nb][0][0][swrow][0]);
                stage16(gwi_l + ko, &sB[nb][0][1][swrow][0]);
                stage16(gwh_h + ko, &sB[nb][1][0][swrow][0]);
                stage16(gwh_l + ko, &sB[nb][1][1][swrow][0]);
                stage16(ga + ko,    &sA[nb][adig][awrow][0]);
                asm volatile("s_waitcnt vmcnt(5)" ::: "memory");
            } else {
                asm volatile("s_waitcnt vmcnt(0)" ::: "memory");
            }
            asm volatile("s_barrier" ::: "memory");

            const int kseg = (lane >> 4) * 16;
            int4v bih[2], bil[2], bhh[2], bhl[2];
            #pragma unroll
            for (int j = 0; j < 2; ++j) {
                const int col = wj * 32 + j * 16 + (lane & 15);
                const int ks  = kseg ^ (((col >> 1) & 3) << 4);
                bih[j] = *(const int4v*)&sB[cur][0][0][col][ks];
                bil[j] = *(const int4v*)&sB[cur][0][1][col][ks];
                bhh[j] = *(const int4v*)&sB[cur][1][0][col][ks];
                bhl[j] = *(const int4v*)&sB[cur][1][1][col][ks];
            }
            __builtin_amdgcn_s_setprio(1);
            #pragma unroll
            for (int i = 0; i < 2; ++i) {
                const int row = wi * 32 + i * 16 + (lane & 15);
                const int ks  = kseg ^ (((row >> 1) & 3) << 4);
                int4v ahf = *(const int4v*)&sA[cur][0][row][ks];
                int4v alf = *(const int4v*)&sA[cur][1][row][ks];
                #pragma unroll
                for (int j = 0; j < 2; ++j) {
                    Pi2[i][j] = __builtin_amdgcn_mfma_i32_16x16x64_i8(ahf, bih[j], Pi2[i][j], 0, 0, 0);
                    Pi1[i][j] = __builtin_amdgcn_mfma_i32_16x16x64_i8(ahf, bil[j], Pi1[i][j], 0, 0, 0);
                    Pi1[i][j] = __builtin_amdgcn_mfma_i32_16x16x64_i8(alf, bih[j], Pi1[i][j], 0, 0, 0);
                    Ph2[i][j] = __builtin_amdgcn_mfma_i32_16x16x64_i8(ahf, bhh[j], Ph2[i][j], 0, 0, 0);
                    Ph1[i][j] = __builtin_amdgcn_mfma_i32_16x16x64_i8(ahf, bhl[j], Ph1[i][j], 0, 0, 0);
                    Ph1[i][j] = __builtin_amdgcn_mfma_i32_16x16x64_i8(alf, bhh[j], Ph1[i][j], 0, 0, 0);
                }
            }
            __builtin_amdgcn_s_setprio(0);
            asm volatile("s_barrier" ::: "memory");
        }

        // epilogue: v = sigmoid(ki) * g(kh) -> u16 (scale 8192), LDS transpose
        #pragma unroll
        for (int j = 0; j < 2; ++j) {
            const int lc = wj * 32 + j * 16 + (lane & 15);
            const float bvi = biv[n0 + lc];
            const float bvh = bhv[n0 + lc];
            #pragma unroll
            for (int i = 0; i < 2; ++i) {
                #pragma unroll
                for (int r = 0; r < 4; ++r) {
                    const float ki = (float)Pi2[i][j][r] * c2 + (float)Pi1[i][j][r] * c1 + bvi;
                    const float kh = (float)Ph2[i][j][r] * c2 + (float)Ph1[i][j][r] * c1 + bvh;
                    const float v  = sigmoidf_(ki) * gfun_(kh);
                    const int lr = wi * 32 + i * 16 + (lane >> 4) * 4 + r;
                    lds16[lr][lc] = (unsigned short)fminf(rintf(v * 8192.0f), 65535.0f);
                }
            }
        }
        __syncthreads();
        const int r  = tid >> 3;
        const int cq = tid & 7;
        #pragma unroll
        for (int it = 0; it < 2; ++it) {
            const int ci = cq + it * 8;
            ushort8v vv = *(const ushort8v*)&lds16[r][ci * 8];
            *(ushort8v*)&vb[(size_t)(m0 + r) * DIM + n0 + ci * 8] = vv;
        }
    }
}

// v stored at scale 8192
#define VSCALE (1.0f / 8192.0f)

// ---------------- scan kernels (r5-proven, occupancy-rebuilt) ----------------
__global__ __launch_bounds__(256) void scan_pass1(
    const float* __restrict__ fb, const unsigned short* __restrict__ vb,
    float* __restrict__ Ach, float* __restrict__ Bch)
{
    const int dq  = threadIdx.x & 127;            // d/4
    const int sub = threadIdx.x >> 7;
    const int c = blockIdx.x * 2 + sub;
    const int b = blockIdx.y;
    const int d = dq * 4;
    float A[4] = {1.f, 1.f, 1.f, 1.f};
    float B[4] = {0.f, 0.f, 0.f, 0.f};
    size_t base = ((size_t)(b * SEQ + c * CLEN)) * DIM + d;
    #pragma unroll 4
    for (int t = 0; t < CLEN; ++t) {
        float4  f4 = *(const float4*)&fb[base + (size_t)t * DIM];
        ushort4 v4 = *(const ushort4*)&vb[base + (size_t)t * DIM];
        float f[4] = {f4.x, f4.y, f4.z, f4.w};
        float v[4] = {(float)v4.x * VSCALE, (float)v4.y * VSCALE,
                      (float)v4.z * VSCALE, (float)v4.w * VSCALE};
        #pragma unroll
        for (int e = 0; e < 4; ++e) { B[e] = fmaf(f[e], B[e], v[e]); A[e] *= f[e]; }
    }
    const size_t idx = (size_t)(b * NCHUNK + c) * DIM + d;
    *(float4*)&Ach[idx] = *(float4*)A;
    *(float4*)&Bch[idx] = *(float4*)B;
}

// pass2: hierarchical chunk-carry in one kernel (see r5 notes).
__global__ __launch_bounds__(1024) void scan_pass2(
    const float* __restrict__ pre_h,
    const float* __restrict__ Ach, const float* __restrict__ Bch,
    float* __restrict__ carry)
{
    __shared__ float As[NSEG][33], Bs[NSEG][33];
    const int b    = blockIdx.y;
    const int dgrp = blockIdx.x;
    const int seg  = threadIdx.x >> 5;
    const int dl   = threadIdx.x & 31;
    const int d    = dgrp * 32 + dl;
    const int c0   = seg * 16;

    float A = 1.0f, Bv = 0.0f;
    #pragma unroll 4
    for (int cc = 0; cc < 16; ++cc) {
        const size_t ix = (size_t)(b * NCHUNK + c0 + cc) * DIM + d;
        const float a  = Ach[ix];
        const float bb = Bch[ix];
        Bv = fmaf(a, Bv, bb);
        A *= a;
    }
    As[seg][dl] = A;
    Bs[seg][dl] = Bv;
    __syncthreads();

    float Ai = A, Bi = Bv;
    #pragma unroll
    for (int s = 1; s < NSEG; s <<= 1) {
        float Al = 1.0f, Bl = 0.0f;
        const bool act = (seg >= s);
        if (act) { Al = As[seg - s][dl]; Bl = Bs[seg - s][dl]; }
        __syncthreads();
        if (act) {
            Bi = fmaf(Ai, Bl, Bi);
            Ai = Ai * Al;
            As[seg][dl] = Ai;
            Bs[seg][dl] = Bi;
        }
        __syncthreads();
    }

    const float h0 = gfun_(pre_h[b * DIM + d]);
    float h;
    if (seg == 0) h = h0;
    else          h = fmaf(As[seg - 1][dl], h0, Bs[seg - 1][dl]);

    #pragma unroll 4
    for (int cc = 0; cc < 16; ++cc) {
        const size_t ix = (size_t)(b * NCHUNK + c0 + cc) * DIM + d;
        carry[ix] = h;
        h = fmaf(Ach[ix], h, Bch[ix]);
    }
}

__global__ __launch_bounds__(256) void scan_pass3(
    const float* __restrict__ fb, const unsigned short* __restrict__ vb,
    const float* __restrict__ carry, float* __restrict__ out)
{
    const int dq  = threadIdx.x & 127;
    const int sub = threadIdx.x >> 7;
    const int c = blockIdx.x * 2 + sub;
    const int b = blockIdx.y;
    const int d = dq * 4;
    float4 h4 = *(const float4*)&carry[(size_t)(b * NCHUNK + c) * DIM + d];
    float h[4] = {h4.x, h4.y, h4.z, h4.w};
    size_t base = ((size_t)(b * SEQ + c * CLEN)) * DIM + d;
    #pragma unroll 4
    for (int t = 0; t < CLEN; ++t) {
        float4  f4 = *(const float4*)&fb[base + (size_t)t * DIM];
        ushort4 v4 = *(const ushort4*)&vb[base + (size_t)t * DIM];
        float f[4] = {f4.x, f4.y, f4.z, f4.w};
        float v[4] = {(float)v4.x * VSCALE, (float)v4.y * VSCALE,
                      (float)v4.z * VSCALE, (float)v4.w * VSCALE};
        f4v o;
        #pragma unroll
        for (int e = 0; e < 4; ++e) { h[e] = fmaf(f[e], h[e], v[e]); o[e] = h[e]; }
        __builtin_nontemporal_store(o, (f4v*)&out[base + (size_t)t * DIM]);
    }
}

extern "C" void kernel_launch(void* const* d_in, const int* in_sizes, int n_in,
                              void* d_out, int out_size, void* d_ws, size_t ws_size,
                              hipStream_t stream) {
    const float* x     = (const float*)d_in[0];
    const float* pre_h = (const float*)d_in[1];
    const float* Wf    = (const float*)d_in[2];
    const float* bf    = (const float*)d_in[3];
    const float* Wi    = (const float*)d_in[4];
    const float* bi    = (const float*)d_in[5];
    const float* Wh    = (const float*)d_in[6];
    const float* bh    = (const float*)d_in[7];
    float* out = (float*)d_out;

    char* ws = (char*)d_ws;
    const size_t XQ = (size_t)M_TOT * DIM;                  // 16 MB per i8 plane
    const size_t WQ = (size_t)3 * DD;                       // 768 KB per digit
    const size_t FB = (size_t)M_TOT * DIM * sizeof(float);  // 64 MB fp32 f plane
    const size_t VB = (size_t)M_TOT * DIM * 2;              // 32 MB u16 v plane
    const size_t CH = (size_t)BATCH * NCHUNK * DIM * sizeof(float);  // 4 MB

    char*  xh  = ws;
    char*  xl  = ws + XQ;
    char*  wth = ws + 2 * XQ;
    char*  wtl = ws + 2 * XQ + WQ;
    float* fbuf = (float*)(ws + 2 * XQ + 2 * WQ);
    unsigned short* vbuf = (unsigned short*)((char*)fbuf + FB);
    float* Ach   = (float*)((char*)vbuf + VB);
    float* Bch   = (float*)((char*)Ach + CH);
    float* carry = (float*)((char*)Bch + CH);

    static bool attr_set = false;
    if (!attr_set) {
        hipFuncSetAttribute((const void*)gemm_fih,
                            hipFuncAttributeMaxDynamicSharedMemorySize, 81920);
        attr_set = true;
    }

    quant_all<<<16576, 256, 0, stream>>>(x, xh, xl, Wf, Wi, Wh, wth, wtl);
    gemm_fih<<<3072, 512, 81920, stream>>>(xh, xl, wth, wtl, bf, bi, bh, fbuf, vbuf);
    scan_pass1<<<dim3(NCHUNK / 2, BATCH), 256, 0, stream>>>(fbuf, vbuf, Ach, Bch);
    scan_pass2<<<dim3(DIM / 32, BATCH), 1024, 0, stream>>>(pre_h, Ach, Bch, carry);
    scan_pass3<<<dim3(NCHUNK / 2, BATCH), 256, 0, stream>>>(fbuf, vbuf, carry, out);
}